// Round 1
// baseline (27.954 us; speedup 1.0000x reference)
//
#include <hip/hip_runtime.h>
#include <math.h>

#define BATCH   2048
#define IN_DIM  512
#define NUM_OUT 256
#define SIG     5.0f

#define TB 32          // batch rows per block
#define TO 32          // outputs per block
#define CH 128         // i-chunk staged in LDS
#define LDW (CH + 4)   // pad: dword stride 132 == 4 mod 32 -> conflict-free reads

// S[b,o] = prod_i (1 - sigmoid(SIG*W[o,i]) * (1 - x[b,i]))
// Block: 256 threads, tile TB x TO, thread computes 2b x 2o.
// grid = (2048/32)*(256/32) = 512 blocks = 2 blocks/CU.
__global__ __launch_bounds__(256, 2)
void logic_and_kernel(const float* __restrict__ x,
                      const float* __restrict__ Wr,
                      float* __restrict__ out) {
  __shared__ float uS[TB][LDW];   // u = 1 - x
  __shared__ float wS[TO][LDW];   // W = sigmoid(SIG * W_raw)

  const int tid   = threadIdx.x;
  const int bt    = blockIdx.x >> 3;   // 0..63 batch tile
  const int ot    = blockIdx.x & 7;    // 0..7  out tile
  const int o_thr = tid & 15;          // 0..15
  const int b_thr = tid >> 4;          // 0..15

  const float* xg = x  + (size_t)(bt * TB) * IN_DIM;
  const float* wg = Wr + (size_t)(ot * TO) * IN_DIM;

  float acc00 = 1.f, acc01 = 1.f, acc10 = 1.f, acc11 = 1.f;

  for (int c = 0; c < IN_DIM / CH; ++c) {
    const int i0 = c * CH;

    // ---- stage chunk: 32 rows x 128 cols each of u and W ----
    // 1024 float4 per tile / 256 threads = 4 per thread, coalesced.
    #pragma unroll
    for (int k = 0; k < 4; ++k) {
      const int f   = tid + 256 * k;
      const int row = f >> 5;          // 0..31
      const int c4  = (f & 31) * 4;    // col in chunk

      float4 xv = *(const float4*)(xg + (size_t)row * IN_DIM + i0 + c4);
      float4 uv;
      uv.x = 1.f - xv.x; uv.y = 1.f - xv.y; uv.z = 1.f - xv.z; uv.w = 1.f - xv.w;
      *(float4*)&uS[row][c4] = uv;

      float4 wv = *(const float4*)(wg + (size_t)row * IN_DIM + i0 + c4);
      float4 sv;
      sv.x = 1.f / (1.f + expf(-SIG * wv.x));
      sv.y = 1.f / (1.f + expf(-SIG * wv.y));
      sv.z = 1.f / (1.f + expf(-SIG * wv.z));
      sv.w = 1.f / (1.f + expf(-SIG * wv.w));
      *(float4*)&wS[row][c4] = sv;
    }
    __syncthreads();

    // ---- inner product-accumulate over the chunk ----
    #pragma unroll 4
    for (int ii = 0; ii < CH; ii += 4) {
      const float4 u0 = *(const float4*)&uS[b_thr][ii];
      const float4 u1 = *(const float4*)&uS[b_thr + 16][ii];
      const float4 w0 = *(const float4*)&wS[o_thr][ii];
      const float4 w1 = *(const float4*)&wS[o_thr + 16][ii];

      // z = 1 - W*u  (fma with negated source); tree-multiply to cut dep chains
      {
        float z0 = fmaf(-w0.x, u0.x, 1.f), z1 = fmaf(-w0.y, u0.y, 1.f);
        float z2 = fmaf(-w0.z, u0.z, 1.f), z3 = fmaf(-w0.w, u0.w, 1.f);
        acc00 *= (z0 * z1) * (z2 * z3);
      }
      {
        float z0 = fmaf(-w1.x, u0.x, 1.f), z1 = fmaf(-w1.y, u0.y, 1.f);
        float z2 = fmaf(-w1.z, u0.z, 1.f), z3 = fmaf(-w1.w, u0.w, 1.f);
        acc01 *= (z0 * z1) * (z2 * z3);
      }
      {
        float z0 = fmaf(-w0.x, u1.x, 1.f), z1 = fmaf(-w0.y, u1.y, 1.f);
        float z2 = fmaf(-w0.z, u1.z, 1.f), z3 = fmaf(-w0.w, u1.w, 1.f);
        acc10 *= (z0 * z1) * (z2 * z3);
      }
      {
        float z0 = fmaf(-w1.x, u1.x, 1.f), z1 = fmaf(-w1.y, u1.y, 1.f);
        float z2 = fmaf(-w1.z, u1.z, 1.f), z3 = fmaf(-w1.w, u1.w, 1.f);
        acc11 *= (z0 * z1) * (z2 * z3);
      }
    }

    // Exact early exit: once every acc in the block is exactly 0.0f, further
    // multiplies are idempotent (z is always finite). Doubles as the barrier
    // separating this chunk's LDS reads from the next chunk's writes.
    const int dead = (acc00 == 0.f) & (acc01 == 0.f) &
                     (acc10 == 0.f) & (acc11 == 0.f);
    if (__syncthreads_and(dead)) break;
  }

  const int b0 = bt * TB + b_thr;
  const int o0 = ot * TO + o_thr;
  out[(size_t)b0 * NUM_OUT + o0]             = acc00;
  out[(size_t)b0 * NUM_OUT + o0 + 16]        = acc01;
  out[(size_t)(b0 + 16) * NUM_OUT + o0]      = acc10;
  out[(size_t)(b0 + 16) * NUM_OUT + o0 + 16] = acc11;
}

extern "C" void kernel_launch(void* const* d_in, const int* in_sizes, int n_in,
                              void* d_out, int out_size, void* d_ws, size_t ws_size,
                              hipStream_t stream) {
  const float* x  = (const float*)d_in[0];   // [2048, 512]
  const float* Wr = (const float*)d_in[1];   // [256, 512]
  float* out      = (float*)d_out;           // [2048, 256]

  dim3 grid((BATCH / TB) * (NUM_OUT / TO));  // 64 * 8 = 512
  dim3 block(256);
  logic_and_kernel<<<grid, block, 0, stream>>>(x, Wr, out);
}